// Round 4
// baseline (146.758 us; speedup 1.0000x reference)
//
#include <hip/hip_runtime.h>

// Problem constants (fixed by the reference):
//   input:       [TP=8, NTOK=2048, HIDDEN=8192] f32
//   residual:    [NTOK, HIDDEN] f32
//   norm_weight: [HIDDEN] f32
// Outputs (concatenated in d_out): output [NTOK,HIDDEN], residual_out [NTOK,HIDDEN]
//
// Structure: ONE WAVE PER ROW (no __syncthreads, no LDS). Each 64-lane wave
// holds its row's allreduced+residual values in registers (32 x f32x4 = 128
// VGPR), reduces sum-of-squares with a 6-step shfl_xor butterfly, then
// normalizes and stores. Barrier-free; latency hidden by ILP (9 independent
// 16B streams per iteration), per fill-kernel evidence that ~8 waves/CU with
// deep ILP sustains ~6.9 TB/s.
constexpr int TP     = 8;
constexpr int HIDDEN = 8192;
constexpr int BLOCK  = 256;            // 4 independent waves per block
constexpr int LPT    = HIDDEN / (64 * 4);  // 32 float4 per lane per row
constexpr float EPS  = 1e-6f;

typedef float f32x4 __attribute__((ext_vector_type(4)));

__global__ __launch_bounds__(BLOCK) void ar_residual_rmsnorm_kernel(
    const float* __restrict__ in,         // [TP, ntok, HIDDEN]
    const float* __restrict__ resid,      // [ntok, HIDDEN]
    const float* __restrict__ w,          // [HIDDEN]
    float* __restrict__ out,              // [ntok, HIDDEN]
    float* __restrict__ resid_out,        // [ntok, HIDDEN]
    int ntok)
{
    const int tid  = threadIdx.x;
    const int wid  = tid >> 6;
    const int lane = tid & 63;
    const int row  = blockIdx.x * (BLOCK / 64) + wid;
    const size_t row_off     = (size_t)row * HIDDEN;
    const size_t rank_stride = (size_t)ntok * HIDDEN;

    // Pass 1: allreduce-sum + residual add; result held in registers.
    f32x4 v[LPT];
    f32x4 ssv = {0.f, 0.f, 0.f, 0.f};
    #pragma unroll 4
    for (int p = 0; p < LPT; ++p) {
        const int col = (lane + p * 64) * 4;   // float index, 16B aligned
        const float* base = in + row_off + col;
        f32x4 x0 = __builtin_nontemporal_load((const f32x4*)(base + 0 * rank_stride));
        f32x4 x1 = __builtin_nontemporal_load((const f32x4*)(base + 1 * rank_stride));
        f32x4 x2 = __builtin_nontemporal_load((const f32x4*)(base + 2 * rank_stride));
        f32x4 x3 = __builtin_nontemporal_load((const f32x4*)(base + 3 * rank_stride));
        f32x4 x4 = __builtin_nontemporal_load((const f32x4*)(base + 4 * rank_stride));
        f32x4 x5 = __builtin_nontemporal_load((const f32x4*)(base + 5 * rank_stride));
        f32x4 x6 = __builtin_nontemporal_load((const f32x4*)(base + 6 * rank_stride));
        f32x4 x7 = __builtin_nontemporal_load((const f32x4*)(base + 7 * rank_stride));
        f32x4 rv = __builtin_nontemporal_load((const f32x4*)(resid + row_off + col));
        f32x4 s01 = x0 + x1, s23 = x2 + x3, s45 = x4 + x5, s67 = x6 + x7;
        f32x4 acc = (s01 + s23) + (s45 + s67) + rv;
        v[p] = acc;
        __builtin_nontemporal_store(acc, (f32x4*)(resid_out + row_off + col));
        ssv += acc * acc;   // fmac per component
    }
    float ss = ssv.x + ssv.y + ssv.z + ssv.w;

    // Wave-level butterfly: every lane ends with the row total. No LDS/barrier.
    #pragma unroll
    for (int o = 32; o > 0; o >>= 1) ss += __shfl_xor(ss, o, 64);

    const float inv = rsqrtf(ss * (1.0f / HIDDEN) + EPS);

    // Pass 2: normalize from registers, apply weight (cached), store output.
    #pragma unroll 4
    for (int p = 0; p < LPT; ++p) {
        const int col = (lane + p * 64) * 4;
        f32x4 wv = *(const f32x4*)(w + col);   // reused by all waves -> cached
        f32x4 o4 = v[p] * inv * wv;
        __builtin_nontemporal_store(o4, (f32x4*)(out + row_off + col));
    }
}

extern "C" void kernel_launch(void* const* d_in, const int* in_sizes, int n_in,
                              void* d_out, int out_size, void* d_ws, size_t ws_size,
                              hipStream_t stream) {
    const float* in    = (const float*)d_in[0];
    const float* resid = (const float*)d_in[1];
    const float* w     = (const float*)d_in[2];

    const int hidden = in_sizes[2];          // 8192
    const int ntok   = in_sizes[1] / hidden; // 2048

    float* out       = (float*)d_out;                         // [ntok, hidden]
    float* resid_out = (float*)d_out + (size_t)ntok * hidden; // [ntok, hidden]

    const int rows_per_block = BLOCK / 64;   // 4 (one wave per row)
    ar_residual_rmsnorm_kernel<<<ntok / rows_per_block, BLOCK, 0, stream>>>(
        in, resid, w, out, resid_out, ntok);
}

// Round 5
// 134.010 us; speedup vs baseline: 1.0951x; 1.0951x over previous
//
#include <hip/hip_runtime.h>

// Problem constants (fixed by the reference):
//   input:       [TP=8, NTOK=2048, HIDDEN=8192] f32
//   residual:    [NTOK, HIDDEN] f32
//   norm_weight: [HIDDEN] f32
// Outputs (concatenated in d_out): output [NTOK,HIDDEN], residual_out [NTOK,HIDDEN]
//
// Structure: ONE WAVE PER ROW, barrier-free, NO held row state.
//   Pass 1: stream 8 rank shards + residual (NT loads), sum, REGULAR store of
//           residual_out (allocates in XCD-local L2), accumulate sum-of-squares.
//   Reduce: 6-step shfl_xor butterfly within the wave (no LDS, no barrier).
//   Pass 2: re-read residual_out (L2/L3 hit -- same wave just wrote it),
//           scale by rsqrt * weight, NT-store output.
// No runtime-indexed arrays anywhere -> zero scratch (R4's failure was
// partial-unroll v[p] spilling to local memory).
constexpr int TP     = 8;
constexpr int HIDDEN = 8192;
constexpr int BLOCK  = 256;                // 4 independent waves per block
constexpr int LPT    = HIDDEN / (64 * 4);  // 32 f32x4 iterations per lane
constexpr float EPS  = 1e-6f;

typedef float f32x4 __attribute__((ext_vector_type(4)));

__global__ __launch_bounds__(BLOCK) void ar_residual_rmsnorm_kernel(
    const float* __restrict__ in,         // [TP, ntok, HIDDEN]
    const float* __restrict__ resid,      // [ntok, HIDDEN]
    const float* __restrict__ w,          // [HIDDEN]
    float* __restrict__ out,              // [ntok, HIDDEN]
    float* __restrict__ resid_out,        // [ntok, HIDDEN]
    int ntok)
{
    const int tid  = threadIdx.x;
    const int wid  = tid >> 6;
    const int lane = tid & 63;
    const int row  = blockIdx.x * (BLOCK / 64) + wid;
    const size_t row_off     = (size_t)row * HIDDEN;
    const size_t rank_stride = (size_t)ntok * HIDDEN;

    // Pass 1: allreduce-sum + residual add; nothing held across iterations.
    f32x4 ssv = {0.f, 0.f, 0.f, 0.f};
    #pragma unroll 4
    for (int p = 0; p < LPT; ++p) {
        const int col = (lane + p * 64) * 4;   // float index, 16B aligned
        const float* base = in + row_off + col;
        f32x4 x0 = __builtin_nontemporal_load((const f32x4*)(base + 0 * rank_stride));
        f32x4 x1 = __builtin_nontemporal_load((const f32x4*)(base + 1 * rank_stride));
        f32x4 x2 = __builtin_nontemporal_load((const f32x4*)(base + 2 * rank_stride));
        f32x4 x3 = __builtin_nontemporal_load((const f32x4*)(base + 3 * rank_stride));
        f32x4 x4 = __builtin_nontemporal_load((const f32x4*)(base + 4 * rank_stride));
        f32x4 x5 = __builtin_nontemporal_load((const f32x4*)(base + 5 * rank_stride));
        f32x4 x6 = __builtin_nontemporal_load((const f32x4*)(base + 6 * rank_stride));
        f32x4 x7 = __builtin_nontemporal_load((const f32x4*)(base + 7 * rank_stride));
        f32x4 rv = __builtin_nontemporal_load((const f32x4*)(resid + row_off + col));
        f32x4 s01 = x0 + x1, s23 = x2 + x3, s45 = x4 + x5, s67 = x6 + x7;
        f32x4 acc = (s01 + s23) + (s45 + s67) + rv;
        // Regular (cache-allocating) store: pass 2 re-reads this from L2.
        *(f32x4*)(resid_out + row_off + col) = acc;
        ssv += acc * acc;
    }
    float ss = ssv.x + ssv.y + ssv.z + ssv.w;

    // Wave butterfly: every lane ends with the row total. No LDS, no barrier.
    #pragma unroll
    for (int o = 32; o > 0; o >>= 1) ss += __shfl_xor(ss, o, 64);

    const float inv = rsqrtf(ss * (1.0f / HIDDEN) + EPS);

    // Pass 2: re-read residual_out (L2-hot), apply inv * weight, store output.
    #pragma unroll 4
    for (int p = 0; p < LPT; ++p) {
        const int col = (lane + p * 64) * 4;
        f32x4 acc = *(const f32x4*)(resid_out + row_off + col);  // L2 hit
        f32x4 wv  = *(const f32x4*)(w + col);                    // cached, shared
        f32x4 o4  = acc * inv * wv;
        __builtin_nontemporal_store(o4, (f32x4*)(out + row_off + col));
    }
}

extern "C" void kernel_launch(void* const* d_in, const int* in_sizes, int n_in,
                              void* d_out, int out_size, void* d_ws, size_t ws_size,
                              hipStream_t stream) {
    const float* in    = (const float*)d_in[0];
    const float* resid = (const float*)d_in[1];
    const float* w     = (const float*)d_in[2];

    const int hidden = in_sizes[2];          // 8192
    const int ntok   = in_sizes[1] / hidden; // 2048

    float* out       = (float*)d_out;                         // [ntok, hidden]
    float* resid_out = (float*)d_out + (size_t)ntok * hidden; // [ntok, hidden]

    const int rows_per_block = BLOCK / 64;   // 4 (one wave per row)
    ar_residual_rmsnorm_kernel<<<ntok / rows_per_block, BLOCK, 0, stream>>>(
        in, resid, w, out, resid_out, ntok);
}

// Round 6
// 126.761 us; speedup vs baseline: 1.1578x; 1.0572x over previous
//
#include <hip/hip_runtime.h>

// Problem constants (fixed by the reference):
//   input:       [TP=8, NTOK=2048, HIDDEN=8192] f32
//   residual:    [NTOK, HIDDEN] f32
//   norm_weight: [HIDDEN] f32
// Outputs (concatenated in d_out): output [NTOK,HIDDEN], residual_out [NTOK,HIDDEN]
//
// R6 = R2 champion structure (block-per-row, register-held row, NT streams)
// with ONE change: read/write phase segregation. Pass 1 is pure loads
// (9 streams -> registers); the residual_out stores are issued as a burst
// AFTER the load loop, so their drain overlaps the shfl-reduce + LDS +
// barrier bubble instead of fragmenting the read phase with bus turnarounds.
constexpr int TP     = 8;
constexpr int HIDDEN = 8192;
constexpr int BLOCK  = 256;
constexpr int VPT    = HIDDEN / (BLOCK * 4);  // 8 float4 per thread
constexpr float EPS  = 1e-6f;

typedef float f32x4 __attribute__((ext_vector_type(4)));

__global__ __launch_bounds__(BLOCK) void ar_residual_rmsnorm_kernel(
    const float* __restrict__ in,         // [TP, ntok, HIDDEN]
    const float* __restrict__ resid,      // [ntok, HIDDEN]
    const float* __restrict__ w,          // [HIDDEN]
    float* __restrict__ out,              // [ntok, HIDDEN]
    float* __restrict__ resid_out,        // [ntok, HIDDEN]
    int ntok)
{
    const int row = blockIdx.x;
    const int tid = threadIdx.x;
    const size_t row_off     = (size_t)row * HIDDEN;
    const size_t rank_stride = (size_t)ntok * HIDDEN;

    // Pass 1: PURE READS. Allreduce-sum + residual add into registers,
    // accumulate sum of squares. No stores in this phase.
    f32x4 v[VPT];
    f32x4 ssv = {0.f, 0.f, 0.f, 0.f};
    #pragma unroll
    for (int p = 0; p < VPT; ++p) {
        const int col = (tid + p * BLOCK) * 4;  // float index, 16B aligned
        const float* base = in + row_off + col;
        f32x4 x0 = __builtin_nontemporal_load((const f32x4*)(base + 0 * rank_stride));
        f32x4 x1 = __builtin_nontemporal_load((const f32x4*)(base + 1 * rank_stride));
        f32x4 x2 = __builtin_nontemporal_load((const f32x4*)(base + 2 * rank_stride));
        f32x4 x3 = __builtin_nontemporal_load((const f32x4*)(base + 3 * rank_stride));
        f32x4 x4 = __builtin_nontemporal_load((const f32x4*)(base + 4 * rank_stride));
        f32x4 x5 = __builtin_nontemporal_load((const f32x4*)(base + 5 * rank_stride));
        f32x4 x6 = __builtin_nontemporal_load((const f32x4*)(base + 6 * rank_stride));
        f32x4 x7 = __builtin_nontemporal_load((const f32x4*)(base + 7 * rank_stride));
        f32x4 rv = __builtin_nontemporal_load((const f32x4*)(resid + row_off + col));
        f32x4 s01 = x0 + x1, s23 = x2 + x3, s45 = x4 + x5, s67 = x6 + x7;
        f32x4 acc = (s01 + s23) + (s45 + s67) + rv;
        v[p] = acc;
        ssv += acc * acc;
    }

    // Store burst: residual_out from registers. These drain while the
    // reduce + barrier below execute.
    #pragma unroll
    for (int p = 0; p < VPT; ++p) {
        const int col = (tid + p * BLOCK) * 4;
        __builtin_nontemporal_store(v[p], (f32x4*)(resid_out + row_off + col));
    }

    float ss = ssv.x + ssv.y + ssv.z + ssv.w;

    // Block reduction of ss: butterfly within each 64-lane wave, then LDS.
    #pragma unroll
    for (int o = 32; o > 0; o >>= 1) ss += __shfl_down(ss, o, 64);
    __shared__ float s_ss[BLOCK / 64];
    const int wid = tid >> 6;
    if ((tid & 63) == 0) s_ss[wid] = ss;
    __syncthreads();
    float tot = 0.f;
    #pragma unroll
    for (int i = 0; i < BLOCK / 64; ++i) tot += s_ss[i];

    const float inv = rsqrtf(tot * (1.0f / HIDDEN) + EPS);

    // Pass 2: normalize from registers, apply weight (cached), store output.
    #pragma unroll
    for (int p = 0; p < VPT; ++p) {
        const int col = (tid + p * BLOCK) * 4;
        f32x4 wv = *(const f32x4*)(w + col);   // reused by all blocks -> cached
        f32x4 o4 = v[p] * inv * wv;
        __builtin_nontemporal_store(o4, (f32x4*)(out + row_off + col));
    }
}

extern "C" void kernel_launch(void* const* d_in, const int* in_sizes, int n_in,
                              void* d_out, int out_size, void* d_ws, size_t ws_size,
                              hipStream_t stream) {
    const float* in    = (const float*)d_in[0];
    const float* resid = (const float*)d_in[1];
    const float* w     = (const float*)d_in[2];

    const int hidden = in_sizes[2];          // 8192
    const int ntok   = in_sizes[1] / hidden; // 2048

    float* out       = (float*)d_out;                         // [ntok, hidden]
    float* resid_out = (float*)d_out + (size_t)ntok * hidden; // [ntok, hidden]

    ar_residual_rmsnorm_kernel<<<ntok, BLOCK, 0, stream>>>(
        in, resid, w, out, resid_out, ntok);
}